// Round 16
// baseline (20.521 us; speedup 1.0000x reference)
//
#include <hip/hip_runtime.h>
#include <hip/hip_fp16.h>

// bg: (1,4,32,32,32,16) f32 ; gm: (1,1,128,128,128) f32 ; out: (1,4,128,128,128) f32
//
// v15: x-lerp folded into staging. Tile 8x8x32 (512 thr, 4 vox/thread).
// LDS: per (i,y,z) plane-node: 16 t-slots of 8B {pk(c0,c1), pk(c2,c3)},
// x-interpolated in f32 for that i. Node stride 36 dw (144B, 16B-aligned).
// 320 nodes (8i*4y*10z) = 46080 B -> 3 blocks/CU. Interp reads 4 corners
// (y,z) x {t0, t0+1} = 8 x ds_read_b64 = 64 B/voxel (half of v14).

#define S_ (31.0f / 127.0f)
#define CH_STRIDE 524288
#define TOTAL 2097152

#define NY 4
#define NZ 10
#define NODE_DW 36                  // 16 slots * 2 dw + 4 pad
#define NPLANES (8 * NY * NZ)       // 320
#define LDS_DW (NPLANES * NODE_DW)  // 11520 dw = 46080 B
#define IS (NY * NZ * NODE_DW)      // 1440
#define YS (NZ * NODE_DW)           // 360

#define PK(x, y) __builtin_bit_cast(float, __floats2half2_rn((x), (y)))
#define H2(f) __builtin_bit_cast(__half2, f)

typedef float vf4 __attribute__((ext_vector_type(4)));

__device__ __forceinline__ void nt_store4(float* p, float a, float b, float c, float d) {
    vf4 v; v.x = a; v.y = b; v.z = c; v.w = d;
    __builtin_nontemporal_store(v, (vf4*)p);
}

__global__ __launch_bounds__(512, 6) void bgrid_slice_v15(
    const float* __restrict__ bg,
    const float* __restrict__ gm,
    float* __restrict__ out)
{
    __shared__ __align__(16) float lds[LDS_DW];

    const int tid = threadIdx.x;
    // XCD-chunked swizzle: 1024 blocks, 8 XCDs -> 128 contiguous tiles each.
    const int b = blockIdx.x;
    const int tile = ((b & 7) << 7) + (b >> 3);
    const int bk = tile & 3;
    const int bj = (tile >> 2) & 15;
    const int bi = tile >> 6;

    const int i0 = bi * 8, j0 = bj * 8, k0 = bk * 32;
    const int y_base = (int)((float)j0 * S_);
    const int z_base = (int)((float)k0 * S_);

    // ---- per-thread voxel ids; issue gm load (nt) before staging ----
    const int kq = tid & 7;
    const int lj = (tid >> 3) & 7;
    const int li = tid >> 6;
    const int i = i0 + li, j = j0 + lj;
    const int kk = k0 + (kq << 2);
    const int idx = (i << 14) | (j << 7) | kk;
    const vf4 g4v = __builtin_nontemporal_load((const vf4*)&gm[idx]);
    float4 g4; g4.x = g4v.x; g4.y = g4v.y; g4.z = g4v.z; g4.w = g4v.w;

    // ---- stage: 320 plane-nodes * 4 segs = 1280 items; x-lerp in f32 ----
    // item q: i_loc = q&7 (lanes adjacent in i share x-nodes -> L1 coalesce),
    // r = q>>3: seg = r&3, yz = r>>2 (y = yz/10, z = yz%10).
    #pragma unroll
    for (int it = 0; it < 3; ++it) {
        const int q = tid + (it << 9);
        if (q < 1280) {
            const int i_loc = q & 7;
            const int r = q >> 3;
            const int seg = r & 3;
            const int yz = r >> 2;          // 0..39
            const int y = yz / 10;
            const int z = yz - y * 10;

            const float xf = fminf((float)(i0 + i_loc) * S_, 31.0f);
            const int x0g = (int)xf;
            const float fx = xf - (float)x0g;
            const int x1g = min(x0g + 1, 31);
            const int gy = min(y_base + y, 31);
            const int gz = min(z_base + z, 31);
            const int a0 = (((x0g * 32 + gy) * 32 + gz) << 4) + (seg << 2);
            const int a1 = (((x1g * 32 + gy) * 32 + gz) << 4) + (seg << 2);

            const float4 A0 = *(const float4*)&bg[a0];
            const float4 A1 = *(const float4*)&bg[a0 + CH_STRIDE];
            const float4 A2 = *(const float4*)&bg[a0 + 2 * CH_STRIDE];
            const float4 A3 = *(const float4*)&bg[a0 + 3 * CH_STRIDE];
            const float4 B0 = *(const float4*)&bg[a1];
            const float4 B1 = *(const float4*)&bg[a1 + CH_STRIDE];
            const float4 B2 = *(const float4*)&bg[a1 + 2 * CH_STRIDE];
            const float4 B3 = *(const float4*)&bg[a1 + 3 * CH_STRIDE];

            float4 C0, C1, C2, C3;          // x-lerped, component = t
            C0.x = fmaf(fx, B0.x - A0.x, A0.x); C0.y = fmaf(fx, B0.y - A0.y, A0.y);
            C0.z = fmaf(fx, B0.z - A0.z, A0.z); C0.w = fmaf(fx, B0.w - A0.w, A0.w);
            C1.x = fmaf(fx, B1.x - A1.x, A1.x); C1.y = fmaf(fx, B1.y - A1.y, A1.y);
            C1.z = fmaf(fx, B1.z - A1.z, A1.z); C1.w = fmaf(fx, B1.w - A1.w, A1.w);
            C2.x = fmaf(fx, B2.x - A2.x, A2.x); C2.y = fmaf(fx, B2.y - A2.y, A2.y);
            C2.z = fmaf(fx, B2.z - A2.z, A2.z); C2.w = fmaf(fx, B2.w - A2.w, A2.w);
            C3.x = fmaf(fx, B3.x - A3.x, A3.x); C3.y = fmaf(fx, B3.y - A3.y, A3.y);
            C3.z = fmaf(fx, B3.z - A3.z, A3.z); C3.w = fmaf(fx, B3.w - A3.w, A3.w);

            float4 W0, W1;                  // slots t=4seg..4seg+3 (8B each)
            W0.x = PK(C0.x, C1.x); W0.y = PK(C2.x, C3.x);
            W0.z = PK(C0.y, C1.y); W0.w = PK(C2.y, C3.y);
            W1.x = PK(C0.z, C1.z); W1.y = PK(C2.z, C3.z);
            W1.z = PK(C0.w, C1.w); W1.w = PK(C2.w, C3.w);

            const int d = ((i_loc * NY + y) * NZ + z) * NODE_DW + (seg << 3);
            *(float4*)&lds[d] = W0;
            *(float4*)&lds[d + 4] = W1;
        }
    }
    __syncthreads();

    // ---- interp: y, z, t lerps from this thread's i-plane ----
    const float yf = fminf((float)j * S_, 31.0f);
    const int y0g = (int)yf; const float fy = yf - (float)y0g;
    const int BY0 = (y0g - y_base) * YS;
    const int BY1 = (min(y0g + 1, 31) - y_base) * YS;
    const int PI = li * IS;

    const __half2 Wy0 = __float2half2_rn(1.0f - fy);
    const __half2 Wy1 = __float2half2_rn(fy);

    float o0[4], o1[4], o2[4], o3[4];

#pragma unroll
    for (int v = 0; v < 4; ++v) {
        const float g = (v == 0) ? g4.x : (v == 1) ? g4.y : (v == 2) ? g4.z : g4.w;
        float t = fminf(fmaxf(g * 15.0f, 0.0f), 15.0f);
        const int t0 = min((int)t, 14);
        const float ft = t - (float)t0;
        const __half2 ft2 = __float2half2_rn(ft);

        const float zf = fminf((float)(kk + v) * S_, 31.0f);
        const int z0g = (int)zf;
        const float fz = zf - (float)z0g;
        const int zi0 = z0g - z_base;
        const int zi1 = min(z0g + 1, 31) - z_base;
        const __half2 fz2 = __float2half2_rn(fz);

        const int CZ0 = zi0 * NODE_DW + (t0 << 1);
        const int CZ1 = zi1 * NODE_DW + (t0 << 1);

        // 4 corners (y,z), each lo (t0) + hi (t0+1), 8B
        const float2 c00lo = *(const float2*)&lds[PI + BY0 + CZ0];
        const float2 c00hi = *(const float2*)&lds[PI + BY0 + CZ0 + 2];
        const float2 c01lo = *(const float2*)&lds[PI + BY1 + CZ0];
        const float2 c01hi = *(const float2*)&lds[PI + BY1 + CZ0 + 2];
        const float2 c10lo = *(const float2*)&lds[PI + BY0 + CZ1];
        const float2 c10hi = *(const float2*)&lds[PI + BY0 + CZ1 + 2];
        const float2 c11lo = *(const float2*)&lds[PI + BY1 + CZ1];
        const float2 c11hi = *(const float2*)&lds[PI + BY1 + CZ1 + 2];

        // y-accum per z-plane
        __half2 L01 = __hmul2(Wy0, H2(c00lo.x));
        __half2 L23 = __hmul2(Wy0, H2(c00lo.y));
        __half2 Lh01 = __hmul2(Wy0, H2(c00hi.x));
        __half2 Lh23 = __hmul2(Wy0, H2(c00hi.y));
        L01 = __hfma2(Wy1, H2(c01lo.x), L01);
        L23 = __hfma2(Wy1, H2(c01lo.y), L23);
        Lh01 = __hfma2(Wy1, H2(c01hi.x), Lh01);
        Lh23 = __hfma2(Wy1, H2(c01hi.y), Lh23);

        __half2 M01 = __hmul2(Wy0, H2(c10lo.x));
        __half2 M23 = __hmul2(Wy0, H2(c10lo.y));
        __half2 Mh01 = __hmul2(Wy0, H2(c10hi.x));
        __half2 Mh23 = __hmul2(Wy0, H2(c10hi.y));
        M01 = __hfma2(Wy1, H2(c11lo.x), M01);
        M23 = __hfma2(Wy1, H2(c11lo.y), M23);
        Mh01 = __hfma2(Wy1, H2(c11hi.x), Mh01);
        Mh23 = __hfma2(Wy1, H2(c11hi.y), Mh23);

        // z-blend then t-lerp
        const __half2 R01 = __hfma2(fz2, __hsub2(M01, L01), L01);
        const __half2 R23 = __hfma2(fz2, __hsub2(M23, L23), L23);
        const __half2 Rh01 = __hfma2(fz2, __hsub2(Mh01, Lh01), Lh01);
        const __half2 Rh23 = __hfma2(fz2, __hsub2(Mh23, Lh23), Lh23);

        const __half2 r01 = __hfma2(ft2, __hsub2(Rh01, R01), R01);
        const __half2 r23 = __hfma2(ft2, __hsub2(Rh23, R23), R23);

        o0[v] = __low2float(r01);
        o1[v] = __high2float(r01);
        o2[v] = __low2float(r23);
        o3[v] = __high2float(r23);
    }

    nt_store4(&out[idx],             o0[0], o0[1], o0[2], o0[3]);
    nt_store4(&out[idx + TOTAL],     o1[0], o1[1], o1[2], o1[3]);
    nt_store4(&out[idx + 2 * TOTAL], o2[0], o2[1], o2[2], o2[3]);
    nt_store4(&out[idx + 3 * TOTAL], o3[0], o3[1], o3[2], o3[3]);
}

extern "C" void kernel_launch(void* const* d_in, const int* in_sizes, int n_in,
                              void* d_out, int out_size, void* d_ws, size_t ws_size,
                              hipStream_t stream) {
    const float* bg = (const float*)d_in[0];
    const float* gm = (const float*)d_in[1];
    float* out = (float*)d_out;

    dim3 grid(1024);   // (128/8)*(128/8)*(128/32)
    dim3 block(512);
    bgrid_slice_v15<<<grid, block, 0, stream>>>(bg, gm, out);
}

// Round 17
// 16.393 us; speedup vs baseline: 1.2518x; 1.2518x over previous
//
#include <hip/hip_runtime.h>
#include <hip/hip_fp16.h>

// bg: (1,4,32,32,32,16) f32 ; gm: (1,1,128,128,128) f32 ; out: (1,4,128,128,128) f32
//
// v14 (best, 16.75 us): 8x8x32 tile, 512 thr, 4 vox/thread.
// Staged nodes 4x * 4y * 10z = 160, dup-slot fp16 layout (slot s = 16B
// {t=s: c0..c3, t=s+1: c0..c3}), NODE_DW 68. LDS 43520 B -> 3 blocks/CU
// (24 waves/CU). XCD-chunked swizzle, nt gm loads, nt out stores.
// Interp: 8 x ds_read_b128 per voxel + fp16 xy-accum, z-blend, t-lerp.

#define S_ (31.0f / 127.0f)
#define CH_STRIDE 524288
#define TOTAL 2097152

#define NX 4
#define NY 4
#define NZ 10
#define NNODES (NX * NY * NZ)      // 160
#define NODE_DW 68
#define LDS_DW (NNODES * NODE_DW)  // 10880 dw = 43520 B

#define PK(x, y) __builtin_bit_cast(float, __floats2half2_rn((x), (y)))
#define H2(f) __builtin_bit_cast(__half2, f)

typedef float vf4 __attribute__((ext_vector_type(4)));

__device__ __forceinline__ void nt_store4(float* p, float a, float b, float c, float d) {
    vf4 v; v.x = a; v.y = b; v.z = c; v.w = d;
    __builtin_nontemporal_store(v, (vf4*)p);
}

__global__ __launch_bounds__(512, 6) void bgrid_slice_v14(
    const float* __restrict__ bg,
    const float* __restrict__ gm,
    float* __restrict__ out)
{
    __shared__ __align__(16) float lds[LDS_DW];

    const int tid = threadIdx.x;
    // XCD-chunked swizzle: 1024 blocks, 8 XCDs -> 128 contiguous tiles each.
    const int b = blockIdx.x;
    const int tile = ((b & 7) << 7) + (b >> 3);
    const int bk = tile & 3;
    const int bj = (tile >> 2) & 15;
    const int bi = tile >> 6;

    const int i0 = bi * 8, j0 = bj * 8, k0 = bk * 32;
    const int x_base = (int)((float)i0 * S_);
    const int y_base = (int)((float)j0 * S_);
    const int z_base = (int)((float)k0 * S_);

    // ---- per-thread voxel ids; issue gm load (nt) before staging ----
    const int kq = tid & 7;
    const int lj = (tid >> 3) & 7;
    const int li = tid >> 6;
    const int i = i0 + li, j = j0 + lj;
    const int kk = k0 + (kq << 2);
    const int idx = (i << 14) | (j << 7) | kk;
    const vf4 g4v = __builtin_nontemporal_load((const vf4*)&gm[idx]);
    float4 g4; g4.x = g4v.x; g4.y = g4v.y; g4.z = g4v.z; g4.w = g4v.w;

    // ---- stage: 160 nodes * 4 segments = 640 items ----
    #pragma unroll
    for (int it = 0; it < 2; ++it) {
        const int q = tid + (it << 9);
        if (q < 640) {
            const int s4 = q & 3;            // t segment: t = 4*s4 .. 4*s4+3
            const int node = q >> 2;         // 0..159
            const int a = node / 40;
            const int rem = node - a * 40;
            const int bb = rem / 10;
            const int cz = rem - bb * 10;
            const int gx = min(x_base + a, 31);
            const int gy = min(y_base + bb, 31);
            const int gz = min(z_base + cz, 31);
            const int gbase = (((gx * 32 + gy) * 32 + gz) << 4) + (s4 << 2);

            const float4 L0 = *(const float4*)&bg[gbase];
            const float4 L1 = *(const float4*)&bg[gbase + CH_STRIDE];
            const float4 L2 = *(const float4*)&bg[gbase + 2 * CH_STRIDE];
            const float4 L3 = *(const float4*)&bg[gbase + 3 * CH_STRIDE];

            float2 p0, p1, p2, p3;           // lo2(t) for t = 4*s4+0..3
            p0.x = PK(L0.x, L1.x); p0.y = PK(L2.x, L3.x);
            p1.x = PK(L0.y, L1.y); p1.y = PK(L2.y, L3.y);
            p2.x = PK(L0.z, L1.z); p2.y = PK(L2.z, L3.z);
            p3.x = PK(L0.w, L1.w); p3.y = PK(L2.w, L3.w);

            const int s0 = node * NODE_DW + (s4 << 4);   // dw of slot 4*s4
            float4 w;
            w.x = p0.x; w.y = p0.y; w.z = p1.x; w.w = p1.y;
            *(float4*)&lds[s0] = w;                       // slot 4s4
            w.x = p1.x; w.y = p1.y; w.z = p2.x; w.w = p2.y;
            *(float4*)&lds[s0 + 4] = w;                   // slot 4s4+1
            w.x = p2.x; w.y = p2.y; w.z = p3.x; w.w = p3.y;
            *(float4*)&lds[s0 + 8] = w;                   // slot 4s4+2
            if (s4 < 3) *(float2*)&lds[s0 + 12] = p3;     // slot 4s4+3 lo
            if (s4 > 0) *(float2*)&lds[s0 - 2]  = p0;     // slot 4s4-1 hi
        }
    }
    __syncthreads();

    // ---- interp ----
    const float xf = fminf((float)i * S_, 31.0f);
    const float yf = fminf((float)j * S_, 31.0f);
    const int x0g = (int)xf; const float fx = xf - (float)x0g;
    const int y0g = (int)yf; const float fy = yf - (float)y0g;
    const int xi0 = x0g - x_base, xi1 = min(x0g + 1, 31) - x_base;
    const int yi0 = y0g - y_base, yi1 = min(y0g + 1, 31) - y_base;

    const int AX0 = xi0 * (NY * NZ * NODE_DW);
    const int AX1 = xi1 * (NY * NZ * NODE_DW);
    const int BY0 = yi0 * (NZ * NODE_DW);
    const int BY1 = yi1 * (NZ * NODE_DW);

    const float wx1 = fx, wx0 = 1.0f - fx;
    const float wy1 = fy, wy0 = 1.0f - fy;
    const __half2 W00 = __float2half2_rn(wx0 * wy0);
    const __half2 W01 = __float2half2_rn(wx0 * wy1);
    const __half2 W10 = __float2half2_rn(wx1 * wy0);
    const __half2 W11 = __float2half2_rn(wx1 * wy1);

    float o0[4], o1[4], o2[4], o3[4];

#pragma unroll
    for (int v = 0; v < 4; ++v) {
        const float g = (v == 0) ? g4.x : (v == 1) ? g4.y : (v == 2) ? g4.z : g4.w;
        float t = fminf(fmaxf(g * 15.0f, 0.0f), 15.0f);
        const int t0 = min((int)t, 14);
        const float ft = t - (float)t0;
        const __half2 ft2 = __float2half2_rn(ft);

        const float zf = fminf((float)(kk + v) * S_, 31.0f);
        const int z0g = (int)zf;
        const float fz = zf - (float)z0g;
        const int zi0 = z0g - z_base;
        const int zi1 = min(z0g + 1, 31) - z_base;
        const __half2 fz2 = __float2half2_rn(fz);

        const int CZ0 = zi0 * NODE_DW + (t0 << 2);
        const int CZ1 = zi1 * NODE_DW + (t0 << 2);

        const float4 a00 = *(const float4*)&lds[AX0 + BY0 + CZ0];
        const float4 a01 = *(const float4*)&lds[AX0 + BY1 + CZ0];
        const float4 a10 = *(const float4*)&lds[AX1 + BY0 + CZ0];
        const float4 a11 = *(const float4*)&lds[AX1 + BY1 + CZ0];
        const float4 b00 = *(const float4*)&lds[AX0 + BY0 + CZ1];
        const float4 b01 = *(const float4*)&lds[AX0 + BY1 + CZ1];
        const float4 b10 = *(const float4*)&lds[AX1 + BY0 + CZ1];
        const float4 b11 = *(const float4*)&lds[AX1 + BY1 + CZ1];

        __half2 Plo01 = __hmul2(W00, H2(a00.x));
        __half2 Plo23 = __hmul2(W00, H2(a00.y));
        __half2 Phi01 = __hmul2(W00, H2(a00.z));
        __half2 Phi23 = __hmul2(W00, H2(a00.w));
        Plo01 = __hfma2(W01, H2(a01.x), Plo01);
        Plo23 = __hfma2(W01, H2(a01.y), Plo23);
        Phi01 = __hfma2(W01, H2(a01.z), Phi01);
        Phi23 = __hfma2(W01, H2(a01.w), Phi23);
        Plo01 = __hfma2(W10, H2(a10.x), Plo01);
        Plo23 = __hfma2(W10, H2(a10.y), Plo23);
        Phi01 = __hfma2(W10, H2(a10.z), Phi01);
        Phi23 = __hfma2(W10, H2(a10.w), Phi23);
        Plo01 = __hfma2(W11, H2(a11.x), Plo01);
        Plo23 = __hfma2(W11, H2(a11.y), Plo23);
        Phi01 = __hfma2(W11, H2(a11.z), Phi01);
        Phi23 = __hfma2(W11, H2(a11.w), Phi23);

        __half2 Qlo01 = __hmul2(W00, H2(b00.x));
        __half2 Qlo23 = __hmul2(W00, H2(b00.y));
        __half2 Qhi01 = __hmul2(W00, H2(b00.z));
        __half2 Qhi23 = __hmul2(W00, H2(b00.w));
        Qlo01 = __hfma2(W01, H2(b01.x), Qlo01);
        Qlo23 = __hfma2(W01, H2(b01.y), Qlo23);
        Qhi01 = __hfma2(W01, H2(b01.z), Qhi01);
        Qhi23 = __hfma2(W01, H2(b01.w), Qhi23);
        Qlo01 = __hfma2(W10, H2(b10.x), Qlo01);
        Qlo23 = __hfma2(W10, H2(b10.y), Qlo23);
        Qhi01 = __hfma2(W10, H2(b10.z), Qhi01);
        Qhi23 = __hfma2(W10, H2(b10.w), Qhi23);
        Qlo01 = __hfma2(W11, H2(b11.x), Qlo01);
        Qlo23 = __hfma2(W11, H2(b11.y), Qlo23);
        Qhi01 = __hfma2(W11, H2(b11.z), Qhi01);
        Qhi23 = __hfma2(W11, H2(b11.w), Qhi23);

        const __half2 Rlo01 = __hfma2(fz2, __hsub2(Qlo01, Plo01), Plo01);
        const __half2 Rlo23 = __hfma2(fz2, __hsub2(Qlo23, Plo23), Plo23);
        const __half2 Rhi01 = __hfma2(fz2, __hsub2(Qhi01, Phi01), Phi01);
        const __half2 Rhi23 = __hfma2(fz2, __hsub2(Qhi23, Phi23), Phi23);

        const __half2 r01 = __hfma2(ft2, __hsub2(Rhi01, Rlo01), Rlo01);
        const __half2 r23 = __hfma2(ft2, __hsub2(Rhi23, Rlo23), Rlo23);

        o0[v] = __low2float(r01);
        o1[v] = __high2float(r01);
        o2[v] = __low2float(r23);
        o3[v] = __high2float(r23);
    }

    nt_store4(&out[idx],             o0[0], o0[1], o0[2], o0[3]);
    nt_store4(&out[idx + TOTAL],     o1[0], o1[1], o1[2], o1[3]);
    nt_store4(&out[idx + 2 * TOTAL], o2[0], o2[1], o2[2], o2[3]);
    nt_store4(&out[idx + 3 * TOTAL], o3[0], o3[1], o3[2], o3[3]);
}

extern "C" void kernel_launch(void* const* d_in, const int* in_sizes, int n_in,
                              void* d_out, int out_size, void* d_ws, size_t ws_size,
                              hipStream_t stream) {
    const float* bg = (const float*)d_in[0];
    const float* gm = (const float*)d_in[1];
    float* out = (float*)d_out;

    dim3 grid(1024);   // (128/8)*(128/8)*(128/32)
    dim3 block(512);
    bgrid_slice_v14<<<grid, block, 0, stream>>>(bg, gm, out);
}